// Round 3
// baseline (840.181 us; speedup 1.0000x reference)
//
#include <hip/hip_runtime.h>

// Problem constants (fixed by the reference)
static constexpr int NN  = 50000;   // nodes (divisible by 4)
static constexpr int EE  = 800000;  // edges
static constexpr int CIN = 96;      // input channels
static constexpr int L1C = 70, S1 = 72;  // TAG layer 1 out, padded stride
static constexpr int L2C = 43, S2 = 44;  // TAG layer 2 out, padded stride

// ---------------------------------------------------------------- preprocessing

__global__ void hist_kernel(const int* __restrict__ col, int* __restrict__ deg, int E) {
    int e = blockIdx.x * blockDim.x + threadIdx.x;
    if (e < E) atomicAdd(&deg[col[e]], 1);
}

static constexpr int SB = 256;  // scan block size

__global__ void reduce_kernel(const int* __restrict__ deg, int* __restrict__ bsum, int n) {
    __shared__ int sd[SB];
    int i = blockIdx.x * SB + threadIdx.x;
    sd[threadIdx.x] = (i < n) ? deg[i] : 0;
    __syncthreads();
    for (int s = SB / 2; s > 0; s >>= 1) {
        if (threadIdx.x < s) sd[threadIdx.x] += sd[threadIdx.x + s];
        __syncthreads();
    }
    if (threadIdx.x == 0) bsum[blockIdx.x] = sd[0];
}

__global__ void scan_sums_kernel(int* __restrict__ bsum, int nb) {
    __shared__ int sd[SB];
    int v = (threadIdx.x < nb) ? bsum[threadIdx.x] : 0;
    sd[threadIdx.x] = v;
    __syncthreads();
    for (int s = 1; s < SB; s <<= 1) {
        int t = (threadIdx.x >= s) ? sd[threadIdx.x - s] : 0;
        __syncthreads();
        sd[threadIdx.x] += t;
        __syncthreads();
    }
    if (threadIdx.x < nb) bsum[threadIdx.x] = sd[threadIdx.x] - v;  // exclusive
}

__global__ void block_scan_kernel(const int* __restrict__ deg, const int* __restrict__ bsum,
                                  int* __restrict__ off, int* __restrict__ cursor,
                                  float* __restrict__ dis, float* __restrict__ dis2, int n) {
    __shared__ int sd[SB];
    int i = blockIdx.x * SB + threadIdx.x;
    int v = (i < n) ? deg[i] : 0;
    sd[threadIdx.x] = v;
    __syncthreads();
    for (int s = 1; s < SB; s <<= 1) {
        int t = (threadIdx.x >= s) ? sd[threadIdx.x - s] : 0;
        __syncthreads();
        sd[threadIdx.x] += t;
        __syncthreads();
    }
    if (i < n) {
        int e = bsum[blockIdx.x] + sd[threadIdx.x] - v;
        off[i] = e;
        cursor[i] = e;
        dis[i]  = (v > 0) ? rsqrtf((float)v) : 0.0f;
        dis2[i] = rsqrtf((float)v + 1.0f);
        if (i == n - 1) off[n] = e + v;
    }
}

// pack (src, weight) per edge for both norm variants
__global__ void fill_kernel(const int* __restrict__ row, const int* __restrict__ col,
                            const float* __restrict__ dis, const float* __restrict__ dis2,
                            int* __restrict__ cursor, int2* __restrict__ eTag,
                            int2* __restrict__ eGcn, int E) {
    int e = blockIdx.x * blockDim.x + threadIdx.x;
    if (e < E) {
        int r = row[e], c = col[e];
        int pos = atomicAdd(&cursor[c], 1);
        eTag[pos] = make_int2(r, __float_as_int(dis[r]  * dis[c]));
        eGcn[pos] = make_int2(r, __float_as_int(dis2[r] * dis2[c]));
    }
}

// ------------------------------------------------------------- aggregation
// out[i][:] = (HASADD ? addv[i][:] : 0) + sum_e w_e * in[src_e][:]  (+ ReLU)
// In-place safe for out==addv (each thread reads its addv slot once, then writes).
template <int C, bool HASADD, bool RELU>
__global__ void agg_kernel(const float* __restrict__ in, const float* addv,
                           float* out, const int* __restrict__ off,
                           const int2* __restrict__ ep, int n) {
    constexpr int TPN = C / 4;  // threads per node
    int t = blockIdx.x * blockDim.x + threadIdx.x;
    if (t >= n * TPN) return;
    int node = t / TPN;
    int cc = (t - node * TPN) * 4;
    int beg = off[node], end = off[node + 1];
    float4 a0 = make_float4(0.f, 0.f, 0.f, 0.f);
    float4 a1 = a0, a2 = a0, a3 = a0;
    int e = beg;
    for (; e + 4 <= end; e += 4) {
        int2 p0 = ep[e], p1 = ep[e + 1], p2 = ep[e + 2], p3 = ep[e + 3];
        float w0 = __int_as_float(p0.y), w1 = __int_as_float(p1.y);
        float w2 = __int_as_float(p2.y), w3 = __int_as_float(p3.y);
        float4 v0 = *reinterpret_cast<const float4*>(in + (size_t)p0.x * C + cc);
        float4 v1 = *reinterpret_cast<const float4*>(in + (size_t)p1.x * C + cc);
        float4 v2 = *reinterpret_cast<const float4*>(in + (size_t)p2.x * C + cc);
        float4 v3 = *reinterpret_cast<const float4*>(in + (size_t)p3.x * C + cc);
        a0.x += w0 * v0.x; a0.y += w0 * v0.y; a0.z += w0 * v0.z; a0.w += w0 * v0.w;
        a1.x += w1 * v1.x; a1.y += w1 * v1.y; a1.z += w1 * v1.z; a1.w += w1 * v1.w;
        a2.x += w2 * v2.x; a2.y += w2 * v2.y; a2.z += w2 * v2.z; a2.w += w2 * v2.w;
        a3.x += w3 * v3.x; a3.y += w3 * v3.y; a3.z += w3 * v3.z; a3.w += w3 * v3.w;
    }
    for (; e < end; ++e) {
        int2 p = ep[e];
        float w = __int_as_float(p.y);
        float4 v = *reinterpret_cast<const float4*>(in + (size_t)p.x * C + cc);
        a0.x += w * v.x; a0.y += w * v.y; a0.z += w * v.z; a0.w += w * v.w;
    }
    float4 r = make_float4(a0.x + a1.x + a2.x + a3.x, a0.y + a1.y + a2.y + a3.y,
                           a0.z + a1.z + a2.z + a3.z, a0.w + a1.w + a2.w + a3.w);
    if constexpr (HASADD) {
        float4 ad = *reinterpret_cast<const float4*>(addv + (size_t)node * C + cc);
        r.x += ad.x; r.y += ad.y; r.z += ad.z; r.w += ad.w;
    }
    if constexpr (RELU) {
        r.x = fmaxf(r.x, 0.f); r.y = fmaxf(r.y, 0.f);
        r.z = fmaxf(r.z, 0.f); r.w = fmaxf(r.w, 0.f);
    }
    *reinterpret_cast<float4*>(out + (size_t)node * C + cc) = r;
}

// ----------------------------------------------------------------- matmul
__device__ __forceinline__ void fma4(float4& a, float s, const float4& w) {
    a.x += s * w.x; a.y += s * w.y; a.z += s * w.z; a.w += s * w.w;
}

// out[n0..n0+3, c0..c0+3] = X[n0..n0+3, :] @ W  (+bias). X row stride KR (padded,
// pad cols zero), W is CR x CC row-major, out stride PC (pad cols get zeros).
// 4-node register blocking: 16 FMAs per ds_read_b128.
template <int KR, int CR, int CC, int PC, bool BIAS>
__global__ void mm_kernel(const float* __restrict__ X, const float* __restrict__ W,
                          const float* __restrict__ bias, float* __restrict__ out, int n) {
    constexpr int CP4 = PC / 4;
    __shared__ __align__(16) float Wl[KR * PC];
    __shared__ __align__(16) float bl[PC];
    for (int i = threadIdx.x; i < KR * PC; i += blockDim.x) {
        int k = i / PC, c = i - k * PC;
        Wl[i] = (k < CR && c < CC) ? W[k * CC + c] : 0.f;
    }
    for (int i = threadIdx.x; i < PC; i += blockDim.x)
        bl[i] = (BIAS && i < CC) ? bias[i] : 0.f;
    __syncthreads();
    int idx = blockIdx.x * blockDim.x + threadIdx.x;
    int total = (n >> 2) * CP4;
    if (idx >= total) return;
    int g = idx / CP4;
    int c0 = (idx - g * CP4) * 4;
    int n0 = g * 4;
    const float* x0 = X + (size_t)n0 * KR;
    const float* x1 = x0 + KR;
    const float* x2 = x1 + KR;
    const float* x3 = x2 + KR;
    float4 b4 = *reinterpret_cast<const float4*>(&bl[c0]);
    float4 acc0 = b4, acc1 = b4, acc2 = b4, acc3 = b4;
    #pragma unroll 4
    for (int k4 = 0; k4 < KR / 4; ++k4) {
        float4 xa = *reinterpret_cast<const float4*>(x0 + k4 * 4);
        float4 xb = *reinterpret_cast<const float4*>(x1 + k4 * 4);
        float4 xc = *reinterpret_cast<const float4*>(x2 + k4 * 4);
        float4 xd = *reinterpret_cast<const float4*>(x3 + k4 * 4);
        float4 w0 = *reinterpret_cast<const float4*>(&Wl[(k4 * 4 + 0) * PC + c0]);
        float4 w1 = *reinterpret_cast<const float4*>(&Wl[(k4 * 4 + 1) * PC + c0]);
        float4 w2 = *reinterpret_cast<const float4*>(&Wl[(k4 * 4 + 2) * PC + c0]);
        float4 w3 = *reinterpret_cast<const float4*>(&Wl[(k4 * 4 + 3) * PC + c0]);
        fma4(acc0, xa.x, w0); fma4(acc0, xa.y, w1); fma4(acc0, xa.z, w2); fma4(acc0, xa.w, w3);
        fma4(acc1, xb.x, w0); fma4(acc1, xb.y, w1); fma4(acc1, xb.z, w2); fma4(acc1, xb.w, w3);
        fma4(acc2, xc.x, w0); fma4(acc2, xc.y, w1); fma4(acc2, xc.z, w2); fma4(acc2, xc.w, w3);
        fma4(acc3, xd.x, w0); fma4(acc3, xd.y, w1); fma4(acc3, xd.z, w2); fma4(acc3, xd.w, w3);
    }
    float* o = out + (size_t)n0 * PC + c0;
    *reinterpret_cast<float4*>(o) = acc0;
    *reinterpret_cast<float4*>(o + PC) = acc1;
    *reinterpret_cast<float4*>(o + 2 * PC) = acc2;
    *reinterpret_cast<float4*>(o + 3 * PC) = acc3;
}

// y[n, 0:16] = o2 @ Wmu ; y[n, 16:32] = o2 @ Wls  (bias added in final kernel)
__global__ void head_mm_kernel(const float* __restrict__ X, const float* __restrict__ Wmu,
                               const float* __restrict__ Wls, float* __restrict__ out, int n) {
    __shared__ __align__(16) float Wl[S2 * 32];
    for (int i = threadIdx.x; i < S2 * 32; i += blockDim.x) {
        int k = i >> 5, c = i & 31;
        Wl[i] = (k < L2C) ? ((c < 16) ? Wmu[k * 16 + c] : Wls[k * 16 + (c - 16)]) : 0.f;
    }
    __syncthreads();
    int idx = blockIdx.x * blockDim.x + threadIdx.x;
    int total = (n >> 2) * 8;
    if (idx >= total) return;
    int g = idx >> 3;
    int c0 = (idx & 7) * 4;
    int n0 = g * 4;
    const float* x0 = X + (size_t)n0 * S2;
    const float* x1 = x0 + S2;
    const float* x2 = x1 + S2;
    const float* x3 = x2 + S2;
    float4 z = make_float4(0.f, 0.f, 0.f, 0.f);
    float4 acc0 = z, acc1 = z, acc2 = z, acc3 = z;
    #pragma unroll 4
    for (int k4 = 0; k4 < S2 / 4; ++k4) {
        float4 xa = *reinterpret_cast<const float4*>(x0 + k4 * 4);
        float4 xb = *reinterpret_cast<const float4*>(x1 + k4 * 4);
        float4 xc = *reinterpret_cast<const float4*>(x2 + k4 * 4);
        float4 xd = *reinterpret_cast<const float4*>(x3 + k4 * 4);
        float4 w0 = *reinterpret_cast<const float4*>(&Wl[(k4 * 4 + 0) * 32 + c0]);
        float4 w1 = *reinterpret_cast<const float4*>(&Wl[(k4 * 4 + 1) * 32 + c0]);
        float4 w2 = *reinterpret_cast<const float4*>(&Wl[(k4 * 4 + 2) * 32 + c0]);
        float4 w3 = *reinterpret_cast<const float4*>(&Wl[(k4 * 4 + 3) * 32 + c0]);
        fma4(acc0, xa.x, w0); fma4(acc0, xa.y, w1); fma4(acc0, xa.z, w2); fma4(acc0, xa.w, w3);
        fma4(acc1, xb.x, w0); fma4(acc1, xb.y, w1); fma4(acc1, xb.z, w2); fma4(acc1, xb.w, w3);
        fma4(acc2, xc.x, w0); fma4(acc2, xc.y, w1); fma4(acc2, xc.z, w2); fma4(acc2, xc.w, w3);
        fma4(acc3, xd.x, w0); fma4(acc3, xd.y, w1); fma4(acc3, xd.z, w2); fma4(acc3, xd.w, w3);
    }
    float* o = out + (size_t)n0 * 32 + c0;
    *reinterpret_cast<float4*>(o) = acc0;
    *reinterpret_cast<float4*>(o + 32) = acc1;
    *reinterpret_cast<float4*>(o + 64) = acc2;
    *reinterpret_cast<float4*>(o + 96) = acc3;
}

// out = agg + dis2^2 * y + bias ; split interleaved (N,32) -> mu (N,16) ++ logstd (N,16)
__global__ void final_kernel(const float* __restrict__ agg, const float* __restrict__ y,
                             const float* __restrict__ dis2, const float* __restrict__ bmu,
                             const float* __restrict__ bls, float* __restrict__ outp, int n) {
    int idx = blockIdx.x * blockDim.x + threadIdx.x;
    if (idx < n * 32) {
        int nn = idx >> 5, c = idx & 31;
        float d = dis2[nn];
        float v = agg[idx] + d * d * y[idx] + ((c < 16) ? bmu[c] : bls[c - 16]);
        size_t o = (c < 16) ? ((size_t)nn * 16 + c)
                            : ((size_t)n * 16 + (size_t)nn * 16 + (c - 16));
        outp[o] = v;
    }
}

// ------------------------------------------------------------------ launch

extern "C" void kernel_launch(void* const* d_in, const int* in_sizes, int n_in,
                              void* d_out, int out_size, void* d_ws, size_t ws_size,
                              hipStream_t stream) {
    const float* x   = (const float*)d_in[0];
    const int*   ei  = (const int*)d_in[1];
    const float* W1  = (const float*)d_in[2];
    const float* b1  = (const float*)d_in[3];
    const float* W2  = (const float*)d_in[4];
    const float* b2  = (const float*)d_in[5];
    const float* Wmu = (const float*)d_in[6];
    const float* bmu = (const float*)d_in[7];
    const float* Wls = (const float*)d_in[8];
    const float* bls = (const float*)d_in[9];
    float* out = (float*)d_out;

    const int N = NN, E = EE;
    const int* row = ei;
    const int* col = ei + E;

    // workspace carve-up (256B aligned)
    char* p = (char*)d_ws;
    auto alloc = [&](size_t bytes) -> char* {
        char* r = p;
        p += (bytes + 255) & ~(size_t)255;
        return r;
    };
    int*   deg    = (int*)alloc((size_t)N * 4);
    int*   off    = (int*)alloc((size_t)(N + 1) * 4);
    int*   cursor = (int*)alloc((size_t)N * 4);
    int*   bsum   = (int*)alloc((size_t)256 * 4);
    float* dis    = (float*)alloc((size_t)N * 4);
    float* dis2   = (float*)alloc((size_t)N * 4);
    int2*  eTag   = (int2*)alloc((size_t)E * 8);
    int2*  eGcn   = (int2*)alloc((size_t)E * 8);
    float* y0     = (float*)alloc((size_t)N * S1 * 4);
    float* y1     = (float*)alloc((size_t)N * S1 * 4);
    float* y2     = (float*)alloc((size_t)N * S1 * 4);
    float* y3     = (float*)alloc((size_t)N * S1 * 4);
    // overlay: u0..u3 (N*S2 each) live in y1..y3's space (y1..y3 dead by then)
    float* u0 = y1;
    float* u1 = u0 + (size_t)N * S2;
    float* u2 = u1 + (size_t)N * S2;
    float* u3 = u2 + (size_t)N * S2;
    // overlay: head outputs live in u1..u2's space (dead after layer-2 aggs)
    float* yh   = u1;
    float* aggY = u2;

    const int B = 256;
    int gE = (E + B - 1) / B;
    int nb = (N + SB - 1) / SB;  // 196 scan blocks

    // --- graph preprocessing -> CSR by destination
    hipMemsetAsync(deg, 0, (size_t)N * 4, stream);
    hist_kernel<<<gE, B, 0, stream>>>(col, deg, E);
    reduce_kernel<<<nb, SB, 0, stream>>>(deg, bsum, N);
    scan_sums_kernel<<<1, SB, 0, stream>>>(bsum, nb);
    block_scan_kernel<<<nb, SB, 0, stream>>>(deg, bsum, off, cursor, dis, dis2, N);
    fill_kernel<<<gE, B, 0, stream>>>(row, col, dis, dis2, cursor, eTag, eGcn, E);

    // grids
    int gmm1 = ((N / 4) * (S1 / 4) + B - 1) / B;
    int gmm2 = ((N / 4) * (S2 / 4) + B - 1) / B;
    int gmmH = ((N / 4) * 8 + B - 1) / B;
    int ga72 = (N * (S1 / 4) + B - 1) / B;
    int ga44 = (N * (S2 / 4) + B - 1) / B;
    int ga32 = (N * 8 + B - 1) / B;

    // --- TAG layer 1 via Horner: o1 = relu(y0 + A(y1 + A(y2 + A*y3)))
    mm_kernel<CIN, CIN, L1C, S1, true ><<<gmm1, B, 0, stream>>>(x, W1,                 b1, y0, N);
    mm_kernel<CIN, CIN, L1C, S1, false><<<gmm1, B, 0, stream>>>(x, W1 + 1 * CIN * L1C, nullptr, y1, N);
    mm_kernel<CIN, CIN, L1C, S1, false><<<gmm1, B, 0, stream>>>(x, W1 + 2 * CIN * L1C, nullptr, y2, N);
    mm_kernel<CIN, CIN, L1C, S1, false><<<gmm1, B, 0, stream>>>(x, W1 + 3 * CIN * L1C, nullptr, y3, N);
    agg_kernel<S1, true, false><<<ga72, B, 0, stream>>>(y3, y2, y2, off, eTag, N);
    agg_kernel<S1, true, false><<<ga72, B, 0, stream>>>(y2, y1, y1, off, eTag, N);
    agg_kernel<S1, true, true ><<<ga72, B, 0, stream>>>(y1, y0, y0, off, eTag, N);
    // o1 = y0 (stride S1, pad cols zero)

    // --- TAG layer 2 via Horner: o2 = relu(u0 + A(u1 + A(u2 + A*u3)))
    mm_kernel<S1, L1C, L2C, S2, true ><<<gmm2, B, 0, stream>>>(y0, W2,                 b2, u0, N);
    mm_kernel<S1, L1C, L2C, S2, false><<<gmm2, B, 0, stream>>>(y0, W2 + 1 * L1C * L2C, nullptr, u1, N);
    mm_kernel<S1, L1C, L2C, S2, false><<<gmm2, B, 0, stream>>>(y0, W2 + 2 * L1C * L2C, nullptr, u2, N);
    mm_kernel<S1, L1C, L2C, S2, false><<<gmm2, B, 0, stream>>>(y0, W2 + 3 * L1C * L2C, nullptr, u3, N);
    agg_kernel<S2, true, false><<<ga44, B, 0, stream>>>(u3, u2, u2, off, eTag, N);
    agg_kernel<S2, true, false><<<ga44, B, 0, stream>>>(u2, u1, u1, off, eTag, N);
    agg_kernel<S2, true, true ><<<ga44, B, 0, stream>>>(u1, u0, u0, off, eTag, N);
    // o2 = u0 (stride S2, pad col zero)

    // --- GCN heads
    head_mm_kernel<<<gmmH, B, 0, stream>>>(u0, Wmu, Wls, yh, N);
    agg_kernel<32, false, false><<<ga32, B, 0, stream>>>(yh, nullptr, aggY, off, eGcn, N);
    final_kernel<<<(N * 32 + B - 1) / B, B, 0, stream>>>(aggY, yh, dis2, bmu, bls, out, N);
}

// Round 4
// 592.743 us; speedup vs baseline: 1.4174x; 1.4174x over previous
//
#include <hip/hip_runtime.h>

// Problem constants (fixed by the reference)
static constexpr int NN  = 50000;   // nodes (divisible by 4)
static constexpr int EE  = 800000;  // edges
static constexpr int CIN = 96;      // input channels
static constexpr int L1C = 70, S1 = 72;  // TAG layer 1 out, padded stride
static constexpr int L2C = 43, S2 = 44;  // TAG layer 2 out, padded stride

// ---------------------------------------------------------------- preprocessing

__global__ void hist_kernel(const int* __restrict__ col, int* __restrict__ deg, int E) {
    int e = blockIdx.x * blockDim.x + threadIdx.x;
    if (e < E) atomicAdd(&deg[col[e]], 1);
}

static constexpr int SB = 256;  // scan block size

__global__ void reduce_kernel(const int* __restrict__ deg, int* __restrict__ bsum, int n) {
    __shared__ int sd[SB];
    int i = blockIdx.x * SB + threadIdx.x;
    sd[threadIdx.x] = (i < n) ? deg[i] : 0;
    __syncthreads();
    for (int s = SB / 2; s > 0; s >>= 1) {
        if (threadIdx.x < s) sd[threadIdx.x] += sd[threadIdx.x + s];
        __syncthreads();
    }
    if (threadIdx.x == 0) bsum[blockIdx.x] = sd[0];
}

__global__ void scan_sums_kernel(int* __restrict__ bsum, int nb) {
    __shared__ int sd[SB];
    int v = (threadIdx.x < nb) ? bsum[threadIdx.x] : 0;
    sd[threadIdx.x] = v;
    __syncthreads();
    for (int s = 1; s < SB; s <<= 1) {
        int t = (threadIdx.x >= s) ? sd[threadIdx.x - s] : 0;
        __syncthreads();
        sd[threadIdx.x] += t;
        __syncthreads();
    }
    if (threadIdx.x < nb) bsum[threadIdx.x] = sd[threadIdx.x] - v;  // exclusive
}

__global__ void block_scan_kernel(const int* __restrict__ deg, const int* __restrict__ bsum,
                                  int* __restrict__ off, int* __restrict__ cursor,
                                  float* __restrict__ dis, float* __restrict__ dis2, int n) {
    __shared__ int sd[SB];
    int i = blockIdx.x * SB + threadIdx.x;
    int v = (i < n) ? deg[i] : 0;
    sd[threadIdx.x] = v;
    __syncthreads();
    for (int s = 1; s < SB; s <<= 1) {
        int t = (threadIdx.x >= s) ? sd[threadIdx.x - s] : 0;
        __syncthreads();
        sd[threadIdx.x] += t;
        __syncthreads();
    }
    if (i < n) {
        int e = bsum[blockIdx.x] + sd[threadIdx.x] - v;
        off[i] = e;
        cursor[i] = e;
        dis[i]  = (v > 0) ? rsqrtf((float)v) : 0.0f;
        dis2[i] = rsqrtf((float)v + 1.0f);
        if (i == n - 1) off[n] = e + v;
    }
}

// pack (src, weight) per edge for both norm variants
__global__ void fill_kernel(const int* __restrict__ row, const int* __restrict__ col,
                            const float* __restrict__ dis, const float* __restrict__ dis2,
                            int* __restrict__ cursor, int2* __restrict__ eTag,
                            int2* __restrict__ eGcn, int E) {
    int e = blockIdx.x * blockDim.x + threadIdx.x;
    if (e < E) {
        int r = row[e], c = col[e];
        int pos = atomicAdd(&cursor[c], 1);
        eTag[pos] = make_int2(r, __float_as_int(dis[r]  * dis[c]));
        eGcn[pos] = make_int2(r, __float_as_int(dis2[r] * dis2[c]));
    }
}

// ------------------------------------------------------------- aggregation
// out[i][:] = (HASADD ? addv[i][:] : 0) + sum_e w_e * in[src_e][:]  (+ ReLU)
// In-place safe for out==addv (each thread reads its addv slot once, then writes).
template <int C, bool HASADD, bool RELU>
__global__ void agg_kernel(const float* __restrict__ in, const float* addv,
                           float* out, const int* __restrict__ off,
                           const int2* __restrict__ ep, int n) {
    constexpr int TPN = C / 4;  // threads per node
    int t = blockIdx.x * blockDim.x + threadIdx.x;
    if (t >= n * TPN) return;
    int node = t / TPN;
    int cc = (t - node * TPN) * 4;
    int beg = off[node], end = off[node + 1];
    float4 a0 = make_float4(0.f, 0.f, 0.f, 0.f);
    float4 a1 = a0, a2 = a0, a3 = a0;
    int e = beg;
    for (; e + 4 <= end; e += 4) {
        int2 p0 = ep[e], p1 = ep[e + 1], p2 = ep[e + 2], p3 = ep[e + 3];
        float w0 = __int_as_float(p0.y), w1 = __int_as_float(p1.y);
        float w2 = __int_as_float(p2.y), w3 = __int_as_float(p3.y);
        float4 v0 = *reinterpret_cast<const float4*>(in + (size_t)p0.x * C + cc);
        float4 v1 = *reinterpret_cast<const float4*>(in + (size_t)p1.x * C + cc);
        float4 v2 = *reinterpret_cast<const float4*>(in + (size_t)p2.x * C + cc);
        float4 v3 = *reinterpret_cast<const float4*>(in + (size_t)p3.x * C + cc);
        a0.x += w0 * v0.x; a0.y += w0 * v0.y; a0.z += w0 * v0.z; a0.w += w0 * v0.w;
        a1.x += w1 * v1.x; a1.y += w1 * v1.y; a1.z += w1 * v1.z; a1.w += w1 * v1.w;
        a2.x += w2 * v2.x; a2.y += w2 * v2.y; a2.z += w2 * v2.z; a2.w += w2 * v2.w;
        a3.x += w3 * v3.x; a3.y += w3 * v3.y; a3.z += w3 * v3.z; a3.w += w3 * v3.w;
    }
    for (; e < end; ++e) {
        int2 p = ep[e];
        float w = __int_as_float(p.y);
        float4 v = *reinterpret_cast<const float4*>(in + (size_t)p.x * C + cc);
        a0.x += w * v.x; a0.y += w * v.y; a0.z += w * v.z; a0.w += w * v.w;
    }
    float4 r = make_float4(a0.x + a1.x + a2.x + a3.x, a0.y + a1.y + a2.y + a3.y,
                           a0.z + a1.z + a2.z + a3.z, a0.w + a1.w + a2.w + a3.w);
    if constexpr (HASADD) {
        float4 ad = *reinterpret_cast<const float4*>(addv + (size_t)node * C + cc);
        r.x += ad.x; r.y += ad.y; r.z += ad.z; r.w += ad.w;
    }
    if constexpr (RELU) {
        r.x = fmaxf(r.x, 0.f); r.y = fmaxf(r.y, 0.f);
        r.z = fmaxf(r.z, 0.f); r.w = fmaxf(r.w, 0.f);
    }
    *reinterpret_cast<float4*>(out + (size_t)node * C + cc) = r;
}

// ----------------------------------------------------------------- matmul
__device__ __forceinline__ void fma4(float4& a, float s, const float4& w) {
    a.x += s * w.x; a.y += s * w.y; a.z += s * w.z; a.w += s * w.w;
}

// out[node, c0..c0+3] = X[node, :] @ W (+bias). Thread = 1 node x 4-col group
// (round-2 proven mapping: max wave count, short dep chains).
// X row stride KR (pad cols zero), W is CR x CC row-major (LDS image padded to
// KR x PC with zeros), out stride PC (pad cols get zeros / bias 0).
template <int KR, int CR, int CC, int PC, bool BIAS>
__global__ void mm_kernel(const float* __restrict__ X, const float* __restrict__ W,
                          const float* __restrict__ bias, float* __restrict__ out, int n) {
    constexpr int CP4 = PC / 4;
    __shared__ __align__(16) float Wl[KR * PC];
    __shared__ __align__(16) float bl[PC];
    for (int i = threadIdx.x; i < KR * PC; i += blockDim.x) {
        int k = i / PC, c = i - k * PC;
        Wl[i] = (k < CR && c < CC) ? W[k * CC + c] : 0.f;
    }
    for (int i = threadIdx.x; i < PC; i += blockDim.x)
        bl[i] = (BIAS && i < CC) ? bias[i] : 0.f;
    __syncthreads();
    int idx = blockIdx.x * blockDim.x + threadIdx.x;
    if (idx >= n * CP4) return;
    int node = idx / CP4;
    int c0 = (idx - node * CP4) * 4;
    const float* xr = X + (size_t)node * KR;
    float4 acc = *reinterpret_cast<const float4*>(&bl[c0]);
    #pragma unroll 4
    for (int k4 = 0; k4 < KR / 4; ++k4) {
        float4 xv = *reinterpret_cast<const float4*>(xr + k4 * 4);
        float4 w0 = *reinterpret_cast<const float4*>(&Wl[(k4 * 4 + 0) * PC + c0]);
        float4 w1 = *reinterpret_cast<const float4*>(&Wl[(k4 * 4 + 1) * PC + c0]);
        float4 w2 = *reinterpret_cast<const float4*>(&Wl[(k4 * 4 + 2) * PC + c0]);
        float4 w3 = *reinterpret_cast<const float4*>(&Wl[(k4 * 4 + 3) * PC + c0]);
        fma4(acc, xv.x, w0); fma4(acc, xv.y, w1);
        fma4(acc, xv.z, w2); fma4(acc, xv.w, w3);
    }
    *reinterpret_cast<float4*>(out + (size_t)node * PC + c0) = acc;
}

// y[n, 0:16] = o2 @ Wmu ; y[n, 16:32] = o2 @ Wls  (bias added in final kernel)
__global__ void head_mm_kernel(const float* __restrict__ X, const float* __restrict__ Wmu,
                               const float* __restrict__ Wls, float* __restrict__ out, int n) {
    __shared__ __align__(16) float Wl[S2 * 32];
    for (int i = threadIdx.x; i < S2 * 32; i += blockDim.x) {
        int k = i >> 5, c = i & 31;
        Wl[i] = (k < L2C) ? ((c < 16) ? Wmu[k * 16 + c] : Wls[k * 16 + (c - 16)]) : 0.f;
    }
    __syncthreads();
    int idx = blockIdx.x * blockDim.x + threadIdx.x;
    if (idx >= n * 8) return;
    int node = idx >> 3;
    int c0 = (idx & 7) * 4;
    const float* xr = X + (size_t)node * S2;
    float4 acc = make_float4(0.f, 0.f, 0.f, 0.f);
    #pragma unroll 4
    for (int k4 = 0; k4 < S2 / 4; ++k4) {
        float4 xv = *reinterpret_cast<const float4*>(xr + k4 * 4);
        float4 w0 = *reinterpret_cast<const float4*>(&Wl[(k4 * 4 + 0) * 32 + c0]);
        float4 w1 = *reinterpret_cast<const float4*>(&Wl[(k4 * 4 + 1) * 32 + c0]);
        float4 w2 = *reinterpret_cast<const float4*>(&Wl[(k4 * 4 + 2) * 32 + c0]);
        float4 w3 = *reinterpret_cast<const float4*>(&Wl[(k4 * 4 + 3) * 32 + c0]);
        fma4(acc, xv.x, w0); fma4(acc, xv.y, w1);
        fma4(acc, xv.z, w2); fma4(acc, xv.w, w3);
    }
    *reinterpret_cast<float4*>(out + (size_t)node * 32 + c0) = acc;
}

// out = agg + dis2^2 * y + bias ; split interleaved (N,32) -> mu (N,16) ++ logstd (N,16)
__global__ void final_kernel(const float* __restrict__ agg, const float* __restrict__ y,
                             const float* __restrict__ dis2, const float* __restrict__ bmu,
                             const float* __restrict__ bls, float* __restrict__ outp, int n) {
    int idx = blockIdx.x * blockDim.x + threadIdx.x;
    if (idx < n * 32) {
        int nn = idx >> 5, c = idx & 31;
        float d = dis2[nn];
        float v = agg[idx] + d * d * y[idx] + ((c < 16) ? bmu[c] : bls[c - 16]);
        size_t o = (c < 16) ? ((size_t)nn * 16 + c)
                            : ((size_t)n * 16 + (size_t)nn * 16 + (c - 16));
        outp[o] = v;
    }
}

// ------------------------------------------------------------------ launch

extern "C" void kernel_launch(void* const* d_in, const int* in_sizes, int n_in,
                              void* d_out, int out_size, void* d_ws, size_t ws_size,
                              hipStream_t stream) {
    const float* x   = (const float*)d_in[0];
    const int*   ei  = (const int*)d_in[1];
    const float* W1  = (const float*)d_in[2];
    const float* b1  = (const float*)d_in[3];
    const float* W2  = (const float*)d_in[4];
    const float* b2  = (const float*)d_in[5];
    const float* Wmu = (const float*)d_in[6];
    const float* bmu = (const float*)d_in[7];
    const float* Wls = (const float*)d_in[8];
    const float* bls = (const float*)d_in[9];
    float* out = (float*)d_out;

    const int N = NN, E = EE;
    const int* row = ei;
    const int* col = ei + E;

    // workspace carve-up (256B aligned)
    char* p = (char*)d_ws;
    auto alloc = [&](size_t bytes) -> char* {
        char* r = p;
        p += (bytes + 255) & ~(size_t)255;
        return r;
    };
    int*   deg    = (int*)alloc((size_t)N * 4);
    int*   off    = (int*)alloc((size_t)(N + 1) * 4);
    int*   cursor = (int*)alloc((size_t)N * 4);
    int*   bsum   = (int*)alloc((size_t)256 * 4);
    float* dis    = (float*)alloc((size_t)N * 4);
    float* dis2   = (float*)alloc((size_t)N * 4);
    int2*  eTag   = (int2*)alloc((size_t)E * 8);
    int2*  eGcn   = (int2*)alloc((size_t)E * 8);
    float* y0     = (float*)alloc((size_t)N * S1 * 4);
    float* y1     = (float*)alloc((size_t)N * S1 * 4);
    float* y2     = (float*)alloc((size_t)N * S1 * 4);
    float* y3     = (float*)alloc((size_t)N * S1 * 4);
    // overlay: u0..u3 (N*S2 each) live in y1..y3's space (y1..y3 dead by then)
    float* u0 = y1;
    float* u1 = u0 + (size_t)N * S2;
    float* u2 = u1 + (size_t)N * S2;
    float* u3 = u2 + (size_t)N * S2;
    // overlay: head outputs live in u1..u2's space (dead after layer-2 aggs)
    float* yh   = u1;
    float* aggY = u2;

    const int B = 256;
    int gE = (E + B - 1) / B;
    int nb = (N + SB - 1) / SB;  // 196 scan blocks

    // --- graph preprocessing -> CSR by destination
    hipMemsetAsync(deg, 0, (size_t)N * 4, stream);
    hist_kernel<<<gE, B, 0, stream>>>(col, deg, E);
    reduce_kernel<<<nb, SB, 0, stream>>>(deg, bsum, N);
    scan_sums_kernel<<<1, SB, 0, stream>>>(bsum, nb);
    block_scan_kernel<<<nb, SB, 0, stream>>>(deg, bsum, off, cursor, dis, dis2, N);
    fill_kernel<<<gE, B, 0, stream>>>(row, col, dis, dis2, cursor, eTag, eGcn, E);

    // grids (thread = node x 4-col group)
    int gmm1 = (N * (S1 / 4) + B - 1) / B;   // 3516 blocks
    int gmm2 = (N * (S2 / 4) + B - 1) / B;   // 2149 blocks
    int gmmH = (N * 8 + B - 1) / B;          // 1563 blocks
    int ga72 = (N * (S1 / 4) + B - 1) / B;
    int ga44 = (N * (S2 / 4) + B - 1) / B;
    int ga32 = (N * 8 + B - 1) / B;

    // --- TAG layer 1 via Horner: o1 = relu(y0 + A(y1 + A(y2 + A*y3)))
    mm_kernel<CIN, CIN, L1C, S1, true ><<<gmm1, B, 0, stream>>>(x, W1,                 b1, y0, N);
    mm_kernel<CIN, CIN, L1C, S1, false><<<gmm1, B, 0, stream>>>(x, W1 + 1 * CIN * L1C, nullptr, y1, N);
    mm_kernel<CIN, CIN, L1C, S1, false><<<gmm1, B, 0, stream>>>(x, W1 + 2 * CIN * L1C, nullptr, y2, N);
    mm_kernel<CIN, CIN, L1C, S1, false><<<gmm1, B, 0, stream>>>(x, W1 + 3 * CIN * L1C, nullptr, y3, N);
    agg_kernel<S1, true, false><<<ga72, B, 0, stream>>>(y3, y2, y2, off, eTag, N);
    agg_kernel<S1, true, false><<<ga72, B, 0, stream>>>(y2, y1, y1, off, eTag, N);
    agg_kernel<S1, true, true ><<<ga72, B, 0, stream>>>(y1, y0, y0, off, eTag, N);
    // o1 = y0 (stride S1, pad cols zero)

    // --- TAG layer 2 via Horner: o2 = relu(u0 + A(u1 + A(u2 + A*u3)))
    mm_kernel<S1, L1C, L2C, S2, true ><<<gmm2, B, 0, stream>>>(y0, W2,                 b2, u0, N);
    mm_kernel<S1, L1C, L2C, S2, false><<<gmm2, B, 0, stream>>>(y0, W2 + 1 * L1C * L2C, nullptr, u1, N);
    mm_kernel<S1, L1C, L2C, S2, false><<<gmm2, B, 0, stream>>>(y0, W2 + 2 * L1C * L2C, nullptr, u2, N);
    mm_kernel<S1, L1C, L2C, S2, false><<<gmm2, B, 0, stream>>>(y0, W2 + 3 * L1C * L2C, nullptr, u3, N);
    agg_kernel<S2, true, false><<<ga44, B, 0, stream>>>(u3, u2, u2, off, eTag, N);
    agg_kernel<S2, true, false><<<ga44, B, 0, stream>>>(u2, u1, u1, off, eTag, N);
    agg_kernel<S2, true, true ><<<ga44, B, 0, stream>>>(u1, u0, u0, off, eTag, N);
    // o2 = u0 (stride S2, pad col zero)

    // --- GCN heads
    head_mm_kernel<<<gmmH, B, 0, stream>>>(u0, Wmu, Wls, yh, N);
    agg_kernel<32, false, false><<<ga32, B, 0, stream>>>(yh, nullptr, aggY, off, eGcn, N);
    final_kernel<<<(N * 32 + B - 1) / B, B, 0, stream>>>(aggY, yh, dis2, bmu, bls, out, N);
}

// Round 5
// 576.148 us; speedup vs baseline: 1.4583x; 1.0288x over previous
//
#include <hip/hip_runtime.h>

// Problem constants (fixed by the reference)
static constexpr int NN  = 50000;   // nodes (even)
static constexpr int EE  = 800000;  // edges
static constexpr int CIN = 96;      // input channels
static constexpr int L1C = 70, S1 = 72;  // TAG layer 1 out, padded stride
static constexpr int L2C = 43, S2 = 44;  // TAG layer 2 out, padded stride

// ---------------------------------------------------------------- preprocessing

__global__ void hist_kernel(const int* __restrict__ col, int* __restrict__ deg, int E) {
    int e = blockIdx.x * blockDim.x + threadIdx.x;
    if (e < E) atomicAdd(&deg[col[e]], 1);
}

static constexpr int SB = 256;  // scan block size

__global__ void reduce_kernel(const int* __restrict__ deg, int* __restrict__ bsum, int n) {
    __shared__ int sd[SB];
    int i = blockIdx.x * SB + threadIdx.x;
    sd[threadIdx.x] = (i < n) ? deg[i] : 0;
    __syncthreads();
    for (int s = SB / 2; s > 0; s >>= 1) {
        if (threadIdx.x < s) sd[threadIdx.x] += sd[threadIdx.x + s];
        __syncthreads();
    }
    if (threadIdx.x == 0) bsum[blockIdx.x] = sd[0];
}

__global__ void scan_sums_kernel(int* __restrict__ bsum, int nb) {
    __shared__ int sd[SB];
    int v = (threadIdx.x < nb) ? bsum[threadIdx.x] : 0;
    sd[threadIdx.x] = v;
    __syncthreads();
    for (int s = 1; s < SB; s <<= 1) {
        int t = (threadIdx.x >= s) ? sd[threadIdx.x - s] : 0;
        __syncthreads();
        sd[threadIdx.x] += t;
        __syncthreads();
    }
    if (threadIdx.x < nb) bsum[threadIdx.x] = sd[threadIdx.x] - v;  // exclusive
}

__global__ void block_scan_kernel(const int* __restrict__ deg, const int* __restrict__ bsum,
                                  int* __restrict__ off, int* __restrict__ cursor,
                                  float* __restrict__ dis, float* __restrict__ dis2, int n) {
    __shared__ int sd[SB];
    int i = blockIdx.x * SB + threadIdx.x;
    int v = (i < n) ? deg[i] : 0;
    sd[threadIdx.x] = v;
    __syncthreads();
    for (int s = 1; s < SB; s <<= 1) {
        int t = (threadIdx.x >= s) ? sd[threadIdx.x - s] : 0;
        __syncthreads();
        sd[threadIdx.x] += t;
        __syncthreads();
    }
    if (i < n) {
        int e = bsum[blockIdx.x] + sd[threadIdx.x] - v;
        off[i] = e;
        cursor[i] = e;
        dis[i]  = (v > 0) ? rsqrtf((float)v) : 0.0f;
        dis2[i] = rsqrtf((float)v + 1.0f);
        if (i == n - 1) off[n] = e + v;
    }
}

// pack (src, TAG weight) per edge; GCN weights are recomputed on the fly later.
__global__ void fill_kernel(const int* __restrict__ row, const int* __restrict__ col,
                            const float* __restrict__ dis, int* __restrict__ cursor,
                            int2* __restrict__ eTag, int E) {
    int e = blockIdx.x * blockDim.x + threadIdx.x;
    if (e < E) {
        int r = row[e], c = col[e];
        int pos = atomicAdd(&cursor[c], 1);
        eTag[pos] = make_int2(r, __float_as_int(dis[r] * dis[c]));
    }
}

// ------------------------------------------------------------- aggregation
// out[i][:] = (HASADD ? addv[i][:] : 0) + sum_e w_e * in[src_e][:]  (+ ReLU)
// In-place safe for out==addv (each thread reads its addv slot once, then writes).
template <int C, bool HASADD, bool RELU>
__global__ void agg_kernel(const float* __restrict__ in, const float* addv,
                           float* out, const int* __restrict__ off,
                           const int2* __restrict__ ep, int n) {
    constexpr int TPN = C / 4;  // threads per node
    int t = blockIdx.x * blockDim.x + threadIdx.x;
    if (t >= n * TPN) return;
    int node = t / TPN;
    int cc = (t - node * TPN) * 4;
    int beg = off[node], end = off[node + 1];
    float4 a0 = make_float4(0.f, 0.f, 0.f, 0.f);
    float4 a1 = a0, a2 = a0, a3 = a0;
    int e = beg;
    for (; e + 4 <= end; e += 4) {
        int2 p0 = ep[e], p1 = ep[e + 1], p2 = ep[e + 2], p3 = ep[e + 3];
        float w0 = __int_as_float(p0.y), w1 = __int_as_float(p1.y);
        float w2 = __int_as_float(p2.y), w3 = __int_as_float(p3.y);
        float4 v0 = *reinterpret_cast<const float4*>(in + (size_t)p0.x * C + cc);
        float4 v1 = *reinterpret_cast<const float4*>(in + (size_t)p1.x * C + cc);
        float4 v2 = *reinterpret_cast<const float4*>(in + (size_t)p2.x * C + cc);
        float4 v3 = *reinterpret_cast<const float4*>(in + (size_t)p3.x * C + cc);
        a0.x += w0 * v0.x; a0.y += w0 * v0.y; a0.z += w0 * v0.z; a0.w += w0 * v0.w;
        a1.x += w1 * v1.x; a1.y += w1 * v1.y; a1.z += w1 * v1.z; a1.w += w1 * v1.w;
        a2.x += w2 * v2.x; a2.y += w2 * v2.y; a2.z += w2 * v2.z; a2.w += w2 * v2.w;
        a3.x += w3 * v3.x; a3.y += w3 * v3.y; a3.z += w3 * v3.z; a3.w += w3 * v3.w;
    }
    for (; e < end; ++e) {
        int2 p = ep[e];
        float w = __int_as_float(p.y);
        float4 v = *reinterpret_cast<const float4*>(in + (size_t)p.x * C + cc);
        a0.x += w * v.x; a0.y += w * v.y; a0.z += w * v.z; a0.w += w * v.w;
    }
    float4 r = make_float4(a0.x + a1.x + a2.x + a3.x, a0.y + a1.y + a2.y + a3.y,
                           a0.z + a1.z + a2.z + a3.z, a0.w + a1.w + a2.w + a3.w);
    if constexpr (HASADD) {
        float4 ad = *reinterpret_cast<const float4*>(addv + (size_t)node * C + cc);
        r.x += ad.x; r.y += ad.y; r.z += ad.z; r.w += ad.w;
    }
    if constexpr (RELU) {
        r.x = fmaxf(r.x, 0.f); r.y = fmaxf(r.y, 0.f);
        r.z = fmaxf(r.z, 0.f); r.w = fmaxf(r.w, 0.f);
    }
    *reinterpret_cast<float4*>(out + (size_t)node * C + cc) = r;
}

// GCN agg + self-loop + bias + split-store, fused final stage.
// outp[node, c] (mu half / logstd half) =
//   dis2[node] * sum_e dis2[src] * yh[src][c]  +  dis2[node]^2 * yh[node][c] + bias[c]
__global__ void agg_gcn_final_kernel(const float* __restrict__ yh,
                                     const int* __restrict__ off,
                                     const int2* __restrict__ ep,
                                     const float* __restrict__ dis2,
                                     const float* __restrict__ bmu,
                                     const float* __restrict__ bls,
                                     float* __restrict__ outp, int n) {
    int t = blockIdx.x * blockDim.x + threadIdx.x;
    if (t >= n * 8) return;
    int node = t >> 3;
    int cc = (t & 7) * 4;
    int beg = off[node], end = off[node + 1];
    float4 a0 = make_float4(0.f, 0.f, 0.f, 0.f);
    float4 a1 = a0;
    int e = beg;
    for (; e + 2 <= end; e += 2) {
        int s0 = ep[e].x, s1 = ep[e + 1].x;
        float w0 = dis2[s0], w1 = dis2[s1];
        float4 v0 = *reinterpret_cast<const float4*>(yh + (size_t)s0 * 32 + cc);
        float4 v1 = *reinterpret_cast<const float4*>(yh + (size_t)s1 * 32 + cc);
        a0.x += w0 * v0.x; a0.y += w0 * v0.y; a0.z += w0 * v0.z; a0.w += w0 * v0.w;
        a1.x += w1 * v1.x; a1.y += w1 * v1.y; a1.z += w1 * v1.z; a1.w += w1 * v1.w;
    }
    for (; e < end; ++e) {
        int s = ep[e].x;
        float w = dis2[s];
        float4 v = *reinterpret_cast<const float4*>(yh + (size_t)s * 32 + cc);
        a0.x += w * v.x; a0.y += w * v.y; a0.z += w * v.z; a0.w += w * v.w;
    }
    float d = dis2[node];
    float4 yv = *reinterpret_cast<const float4*>(yh + (size_t)node * 32 + cc);
    const float* bp = (cc < 16) ? (bmu + cc) : (bls + cc - 16);
    float4 r;
    r.x = d * (a0.x + a1.x) + d * d * yv.x + bp[0];
    r.y = d * (a0.y + a1.y) + d * d * yv.y + bp[1];
    r.z = d * (a0.z + a1.z) + d * d * yv.z + bp[2];
    r.w = d * (a0.w + a1.w) + d * d * yv.w + bp[3];
    size_t o = (cc < 16) ? ((size_t)node * 16 + cc)
                         : ((size_t)n * 16 + (size_t)node * 16 + (cc - 16));
    *reinterpret_cast<float4*>(outp + o) = r;
}

// ----------------------------------------------------------------- matmul
__device__ __forceinline__ void fma4(float4& a, float s, const float4& w) {
    a.x += s * w.x; a.y += s * w.y; a.z += s * w.z; a.w += s * w.w;
}

// out[n0..n0+1, c0..c0+3] = X[n0..n0+1, :] @ W (+bias).
// Thread = 2 nodes x 4-col group: 8 FMAs per ds_read_b128 (half the LDS traffic
// of 1-node), 450k threads keeps occupancy (round-3's 4-node at 225k regressed).
template <int KR, int CR, int CC, int PC, bool BIAS>
__global__ void mm_kernel(const float* __restrict__ X, const float* __restrict__ W,
                          const float* __restrict__ bias, float* __restrict__ out, int n) {
    constexpr int CP4 = PC / 4;
    __shared__ __align__(16) float Wl[KR * PC];
    __shared__ __align__(16) float bl[PC];
    for (int i = threadIdx.x; i < KR * PC; i += blockDim.x) {
        int k = i / PC, c = i - k * PC;
        Wl[i] = (k < CR && c < CC) ? W[k * CC + c] : 0.f;
    }
    for (int i = threadIdx.x; i < PC; i += blockDim.x)
        bl[i] = (BIAS && i < CC) ? bias[i] : 0.f;
    __syncthreads();
    int idx = blockIdx.x * blockDim.x + threadIdx.x;
    if (idx >= (n >> 1) * CP4) return;
    int pair = idx / CP4;
    int c0 = (idx - pair * CP4) * 4;
    int n0 = pair * 2;
    const float* x0 = X + (size_t)n0 * KR;
    const float* x1 = x0 + KR;
    float4 b4 = *reinterpret_cast<const float4*>(&bl[c0]);
    float4 acc0 = b4, acc1 = b4;
    #pragma unroll 4
    for (int k4 = 0; k4 < KR / 4; ++k4) {
        float4 xa = *reinterpret_cast<const float4*>(x0 + k4 * 4);
        float4 xb = *reinterpret_cast<const float4*>(x1 + k4 * 4);
        float4 w0 = *reinterpret_cast<const float4*>(&Wl[(k4 * 4 + 0) * PC + c0]);
        float4 w1 = *reinterpret_cast<const float4*>(&Wl[(k4 * 4 + 1) * PC + c0]);
        float4 w2 = *reinterpret_cast<const float4*>(&Wl[(k4 * 4 + 2) * PC + c0]);
        float4 w3 = *reinterpret_cast<const float4*>(&Wl[(k4 * 4 + 3) * PC + c0]);
        fma4(acc0, xa.x, w0); fma4(acc0, xa.y, w1); fma4(acc0, xa.z, w2); fma4(acc0, xa.w, w3);
        fma4(acc1, xb.x, w0); fma4(acc1, xb.y, w1); fma4(acc1, xb.z, w2); fma4(acc1, xb.w, w3);
    }
    float* o = out + (size_t)n0 * PC + c0;
    *reinterpret_cast<float4*>(o) = acc0;
    *reinterpret_cast<float4*>(o + PC) = acc1;
}

// y[n, 0:16] = o2 @ Wmu ; y[n, 16:32] = o2 @ Wls  (bias added in fused final agg)
__global__ void head_mm_kernel(const float* __restrict__ X, const float* __restrict__ Wmu,
                               const float* __restrict__ Wls, float* __restrict__ out, int n) {
    __shared__ __align__(16) float Wl[S2 * 32];
    for (int i = threadIdx.x; i < S2 * 32; i += blockDim.x) {
        int k = i >> 5, c = i & 31;
        Wl[i] = (k < L2C) ? ((c < 16) ? Wmu[k * 16 + c] : Wls[k * 16 + (c - 16)]) : 0.f;
    }
    __syncthreads();
    int idx = blockIdx.x * blockDim.x + threadIdx.x;
    if (idx >= (n >> 1) * 8) return;
    int pair = idx >> 3;
    int c0 = (idx & 7) * 4;
    int n0 = pair * 2;
    const float* x0 = X + (size_t)n0 * S2;
    const float* x1 = x0 + S2;
    float4 z = make_float4(0.f, 0.f, 0.f, 0.f);
    float4 acc0 = z, acc1 = z;
    #pragma unroll 4
    for (int k4 = 0; k4 < S2 / 4; ++k4) {
        float4 xa = *reinterpret_cast<const float4*>(x0 + k4 * 4);
        float4 xb = *reinterpret_cast<const float4*>(x1 + k4 * 4);
        float4 w0 = *reinterpret_cast<const float4*>(&Wl[(k4 * 4 + 0) * 32 + c0]);
        float4 w1 = *reinterpret_cast<const float4*>(&Wl[(k4 * 4 + 1) * 32 + c0]);
        float4 w2 = *reinterpret_cast<const float4*>(&Wl[(k4 * 4 + 2) * 32 + c0]);
        float4 w3 = *reinterpret_cast<const float4*>(&Wl[(k4 * 4 + 3) * 32 + c0]);
        fma4(acc0, xa.x, w0); fma4(acc0, xa.y, w1); fma4(acc0, xa.z, w2); fma4(acc0, xa.w, w3);
        fma4(acc1, xb.x, w0); fma4(acc1, xb.y, w1); fma4(acc1, xb.z, w2); fma4(acc1, xb.w, w3);
    }
    float* o = out + (size_t)n0 * 32 + c0;
    *reinterpret_cast<float4*>(o) = acc0;
    *reinterpret_cast<float4*>(o + 32) = acc1;
}

// ------------------------------------------------------------------ launch

extern "C" void kernel_launch(void* const* d_in, const int* in_sizes, int n_in,
                              void* d_out, int out_size, void* d_ws, size_t ws_size,
                              hipStream_t stream) {
    const float* x   = (const float*)d_in[0];
    const int*   ei  = (const int*)d_in[1];
    const float* W1  = (const float*)d_in[2];
    const float* b1  = (const float*)d_in[3];
    const float* W2  = (const float*)d_in[4];
    const float* b2  = (const float*)d_in[5];
    const float* Wmu = (const float*)d_in[6];
    const float* bmu = (const float*)d_in[7];
    const float* Wls = (const float*)d_in[8];
    const float* bls = (const float*)d_in[9];
    float* out = (float*)d_out;

    const int N = NN, E = EE;
    const int* row = ei;
    const int* col = ei + E;

    // workspace carve-up (256B aligned)
    char* p = (char*)d_ws;
    auto alloc = [&](size_t bytes) -> char* {
        char* r = p;
        p += (bytes + 255) & ~(size_t)255;
        return r;
    };
    int*   deg    = (int*)alloc((size_t)N * 4);
    int*   off    = (int*)alloc((size_t)(N + 1) * 4);
    int*   cursor = (int*)alloc((size_t)N * 4);
    int*   bsum   = (int*)alloc((size_t)256 * 4);
    float* dis    = (float*)alloc((size_t)N * 4);
    float* dis2   = (float*)alloc((size_t)N * 4);
    int2*  eTag   = (int2*)alloc((size_t)E * 8);
    float* y0     = (float*)alloc((size_t)N * S1 * 4);
    float* y1     = (float*)alloc((size_t)N * S1 * 4);
    float* y2     = (float*)alloc((size_t)N * S1 * 4);
    float* y3     = (float*)alloc((size_t)N * S1 * 4);
    // overlay: u0..u3 (N*S2 each) live in y1..y3's space (y1..y3 dead by then)
    float* u0 = y1;
    float* u1 = u0 + (size_t)N * S2;
    float* u2 = u1 + (size_t)N * S2;
    float* u3 = u2 + (size_t)N * S2;
    // overlay: head output lives in u1's space (dead after layer-2 aggs)
    float* yh = u1;

    const int B = 256;
    int gE = (E + B - 1) / B;
    int nb = (N + SB - 1) / SB;  // 196 scan blocks

    // --- graph preprocessing -> CSR by destination
    hipMemsetAsync(deg, 0, (size_t)N * 4, stream);
    hist_kernel<<<gE, B, 0, stream>>>(col, deg, E);
    reduce_kernel<<<nb, SB, 0, stream>>>(deg, bsum, N);
    scan_sums_kernel<<<1, SB, 0, stream>>>(bsum, nb);
    block_scan_kernel<<<nb, SB, 0, stream>>>(deg, bsum, off, cursor, dis, dis2, N);
    fill_kernel<<<gE, B, 0, stream>>>(row, col, dis, cursor, eTag, E);

    // grids
    int gmm1 = ((N / 2) * (S1 / 4) + B - 1) / B;
    int gmm2 = ((N / 2) * (S2 / 4) + B - 1) / B;
    int gmmH = ((N / 2) * 8 + B - 1) / B;
    int ga72 = (N * (S1 / 4) + B - 1) / B;
    int ga44 = (N * (S2 / 4) + B - 1) / B;
    int ga32 = (N * 8 + B - 1) / B;

    // --- TAG layer 1 via Horner: o1 = relu(y0 + A(y1 + A(y2 + A*y3)))
    mm_kernel<CIN, CIN, L1C, S1, true ><<<gmm1, B, 0, stream>>>(x, W1,                 b1, y0, N);
    mm_kernel<CIN, CIN, L1C, S1, false><<<gmm1, B, 0, stream>>>(x, W1 + 1 * CIN * L1C, nullptr, y1, N);
    mm_kernel<CIN, CIN, L1C, S1, false><<<gmm1, B, 0, stream>>>(x, W1 + 2 * CIN * L1C, nullptr, y2, N);
    mm_kernel<CIN, CIN, L1C, S1, false><<<gmm1, B, 0, stream>>>(x, W1 + 3 * CIN * L1C, nullptr, y3, N);
    agg_kernel<S1, true, false><<<ga72, B, 0, stream>>>(y3, y2, y2, off, eTag, N);
    agg_kernel<S1, true, false><<<ga72, B, 0, stream>>>(y2, y1, y1, off, eTag, N);
    agg_kernel<S1, true, true ><<<ga72, B, 0, stream>>>(y1, y0, y0, off, eTag, N);
    // o1 = y0 (stride S1, pad cols zero)

    // --- TAG layer 2 via Horner: o2 = relu(u0 + A(u1 + A(u2 + A*u3)))
    mm_kernel<S1, L1C, L2C, S2, true ><<<gmm2, B, 0, stream>>>(y0, W2,                 b2, u0, N);
    mm_kernel<S1, L1C, L2C, S2, false><<<gmm2, B, 0, stream>>>(y0, W2 + 1 * L1C * L2C, nullptr, u1, N);
    mm_kernel<S1, L1C, L2C, S2, false><<<gmm2, B, 0, stream>>>(y0, W2 + 2 * L1C * L2C, nullptr, u2, N);
    mm_kernel<S1, L1C, L2C, S2, false><<<gmm2, B, 0, stream>>>(y0, W2 + 3 * L1C * L2C, nullptr, u3, N);
    agg_kernel<S2, true, false><<<ga44, B, 0, stream>>>(u3, u2, u2, off, eTag, N);
    agg_kernel<S2, true, false><<<ga44, B, 0, stream>>>(u2, u1, u1, off, eTag, N);
    agg_kernel<S2, true, true ><<<ga44, B, 0, stream>>>(u1, u0, u0, off, eTag, N);
    // o2 = u0 (stride S2, pad col zero)

    // --- GCN heads: head matmul, then fused agg+self+bias+split-store
    head_mm_kernel<<<gmmH, B, 0, stream>>>(u0, Wmu, Wls, yh, N);
    agg_gcn_final_kernel<<<ga32, B, 0, stream>>>(yh, off, eTag, dis2, bmu, bls, out, N);
}

// Round 6
// 561.386 us; speedup vs baseline: 1.4966x; 1.0263x over previous
//
#include <hip/hip_runtime.h>

// Problem constants (fixed by the reference)
static constexpr int NN  = 50000;   // nodes (even)
static constexpr int EE  = 800000;  // edges
static constexpr int CIN = 96;      // input channels
static constexpr int L1C = 70, S1 = 72;  // TAG layer 1 out, padded stride
static constexpr int L2C = 43, S2 = 44;  // TAG layer 2 out, padded stride

// ---------------------------------------------------------------- preprocessing

__global__ void hist_kernel(const int* __restrict__ col, int* __restrict__ deg, int E) {
    int e = blockIdx.x * blockDim.x + threadIdx.x;
    if (e < E) atomicAdd(&deg[col[e]], 1);
}

static constexpr int SB = 256;  // scan block size

__global__ void reduce_kernel(const int* __restrict__ deg, int* __restrict__ bsum, int n) {
    __shared__ int sd[SB];
    int i = blockIdx.x * SB + threadIdx.x;
    sd[threadIdx.x] = (i < n) ? deg[i] : 0;
    __syncthreads();
    for (int s = SB / 2; s > 0; s >>= 1) {
        if (threadIdx.x < s) sd[threadIdx.x] += sd[threadIdx.x + s];
        __syncthreads();
    }
    if (threadIdx.x == 0) bsum[blockIdx.x] = sd[0];
}

__global__ void scan_sums_kernel(int* __restrict__ bsum, int nb) {
    __shared__ int sd[SB];
    int v = (threadIdx.x < nb) ? bsum[threadIdx.x] : 0;
    sd[threadIdx.x] = v;
    __syncthreads();
    for (int s = 1; s < SB; s <<= 1) {
        int t = (threadIdx.x >= s) ? sd[threadIdx.x - s] : 0;
        __syncthreads();
        sd[threadIdx.x] += t;
        __syncthreads();
    }
    if (threadIdx.x < nb) bsum[threadIdx.x] = sd[threadIdx.x] - v;  // exclusive
}

__global__ void block_scan_kernel(const int* __restrict__ deg, const int* __restrict__ bsum,
                                  int* __restrict__ off, int* __restrict__ cursor,
                                  float* __restrict__ dis, float* __restrict__ dis2, int n) {
    __shared__ int sd[SB];
    int i = blockIdx.x * SB + threadIdx.x;
    int v = (i < n) ? deg[i] : 0;
    sd[threadIdx.x] = v;
    __syncthreads();
    for (int s = 1; s < SB; s <<= 1) {
        int t = (threadIdx.x >= s) ? sd[threadIdx.x - s] : 0;
        __syncthreads();
        sd[threadIdx.x] += t;
        __syncthreads();
    }
    if (i < n) {
        int e = bsum[blockIdx.x] + sd[threadIdx.x] - v;
        off[i] = e;
        cursor[i] = e;
        dis[i]  = (v > 0) ? rsqrtf((float)v) : 0.0f;
        dis2[i] = rsqrtf((float)v + 1.0f);
        if (i == n - 1) off[n] = e + v;
    }
}

// pack (src, TAG weight) per edge; GCN weights are recomputed on the fly later.
__global__ void fill_kernel(const int* __restrict__ row, const int* __restrict__ col,
                            const float* __restrict__ dis, int* __restrict__ cursor,
                            int2* __restrict__ eTag, int E) {
    int e = blockIdx.x * blockDim.x + threadIdx.x;
    if (e < E) {
        int r = row[e], c = col[e];
        int pos = atomicAdd(&cursor[c], 1);
        eTag[pos] = make_int2(r, __float_as_int(dis[r] * dis[c]));
    }
}

// ------------------------------------------------------------- aggregation
// out[i][:] = (HASADD ? addv[i][:] : 0) + sum_e w_e * in[src_e][:]  (+ ReLU)
// In-place safe for out==addv (each thread reads its addv slot once, then writes).
template <int C, bool HASADD, bool RELU>
__global__ void agg_kernel(const float* __restrict__ in, const float* addv,
                           float* out, const int* __restrict__ off,
                           const int2* __restrict__ ep, int n) {
    constexpr int TPN = C / 4;  // threads per node
    int t = blockIdx.x * blockDim.x + threadIdx.x;
    if (t >= n * TPN) return;
    int node = t / TPN;
    int cc = (t - node * TPN) * 4;
    int beg = off[node], end = off[node + 1];
    float4 a0 = make_float4(0.f, 0.f, 0.f, 0.f);
    float4 a1 = a0, a2 = a0, a3 = a0;
    int e = beg;
    for (; e + 4 <= end; e += 4) {
        int2 p0 = ep[e], p1 = ep[e + 1], p2 = ep[e + 2], p3 = ep[e + 3];
        float w0 = __int_as_float(p0.y), w1 = __int_as_float(p1.y);
        float w2 = __int_as_float(p2.y), w3 = __int_as_float(p3.y);
        float4 v0 = *reinterpret_cast<const float4*>(in + (size_t)p0.x * C + cc);
        float4 v1 = *reinterpret_cast<const float4*>(in + (size_t)p1.x * C + cc);
        float4 v2 = *reinterpret_cast<const float4*>(in + (size_t)p2.x * C + cc);
        float4 v3 = *reinterpret_cast<const float4*>(in + (size_t)p3.x * C + cc);
        a0.x += w0 * v0.x; a0.y += w0 * v0.y; a0.z += w0 * v0.z; a0.w += w0 * v0.w;
        a1.x += w1 * v1.x; a1.y += w1 * v1.y; a1.z += w1 * v1.z; a1.w += w1 * v1.w;
        a2.x += w2 * v2.x; a2.y += w2 * v2.y; a2.z += w2 * v2.z; a2.w += w2 * v2.w;
        a3.x += w3 * v3.x; a3.y += w3 * v3.y; a3.z += w3 * v3.z; a3.w += w3 * v3.w;
    }
    for (; e < end; ++e) {
        int2 p = ep[e];
        float w = __int_as_float(p.y);
        float4 v = *reinterpret_cast<const float4*>(in + (size_t)p.x * C + cc);
        a0.x += w * v.x; a0.y += w * v.y; a0.z += w * v.z; a0.w += w * v.w;
    }
    float4 r = make_float4(a0.x + a1.x + a2.x + a3.x, a0.y + a1.y + a2.y + a3.y,
                           a0.z + a1.z + a2.z + a3.z, a0.w + a1.w + a2.w + a3.w);
    if constexpr (HASADD) {
        float4 ad = *reinterpret_cast<const float4*>(addv + (size_t)node * C + cc);
        r.x += ad.x; r.y += ad.y; r.z += ad.z; r.w += ad.w;
    }
    if constexpr (RELU) {
        r.x = fmaxf(r.x, 0.f); r.y = fmaxf(r.y, 0.f);
        r.z = fmaxf(r.z, 0.f); r.w = fmaxf(r.w, 0.f);
    }
    *reinterpret_cast<float4*>(out + (size_t)node * C + cc) = r;
}

// GCN agg + self-loop + bias + split-store, fused final stage.
__global__ void agg_gcn_final_kernel(const float* __restrict__ yh,
                                     const int* __restrict__ off,
                                     const int2* __restrict__ ep,
                                     const float* __restrict__ dis2,
                                     const float* __restrict__ bmu,
                                     const float* __restrict__ bls,
                                     float* __restrict__ outp, int n) {
    int t = blockIdx.x * blockDim.x + threadIdx.x;
    if (t >= n * 8) return;
    int node = t >> 3;
    int cc = (t & 7) * 4;
    int beg = off[node], end = off[node + 1];
    float4 a0 = make_float4(0.f, 0.f, 0.f, 0.f);
    float4 a1 = a0;
    int e = beg;
    for (; e + 2 <= end; e += 2) {
        int s0 = ep[e].x, s1 = ep[e + 1].x;
        float w0 = dis2[s0], w1 = dis2[s1];
        float4 v0 = *reinterpret_cast<const float4*>(yh + (size_t)s0 * 32 + cc);
        float4 v1 = *reinterpret_cast<const float4*>(yh + (size_t)s1 * 32 + cc);
        a0.x += w0 * v0.x; a0.y += w0 * v0.y; a0.z += w0 * v0.z; a0.w += w0 * v0.w;
        a1.x += w1 * v1.x; a1.y += w1 * v1.y; a1.z += w1 * v1.z; a1.w += w1 * v1.w;
    }
    for (; e < end; ++e) {
        int s = ep[e].x;
        float w = dis2[s];
        float4 v = *reinterpret_cast<const float4*>(yh + (size_t)s * 32 + cc);
        a0.x += w * v.x; a0.y += w * v.y; a0.z += w * v.z; a0.w += w * v.w;
    }
    float d = dis2[node];
    float4 yv = *reinterpret_cast<const float4*>(yh + (size_t)node * 32 + cc);
    const float* bp = (cc < 16) ? (bmu + cc) : (bls + cc - 16);
    float4 r;
    r.x = d * (a0.x + a1.x) + d * d * yv.x + bp[0];
    r.y = d * (a0.y + a1.y) + d * d * yv.y + bp[1];
    r.z = d * (a0.z + a1.z) + d * d * yv.z + bp[2];
    r.w = d * (a0.w + a1.w) + d * d * yv.w + bp[3];
    size_t o = (cc < 16) ? ((size_t)node * 16 + cc)
                         : ((size_t)n * 16 + (size_t)node * 16 + (cc - 16));
    *reinterpret_cast<float4*>(outp + o) = r;
}

// ----------------------------------------------------------------- matmul
__device__ __forceinline__ void fma4(float4& a, float s, const float4& w) {
    a.x += s * w.x; a.y += s * w.y; a.z += s * w.z; a.w += s * w.w;
}

// Fused multi-W matmul: out_w[n0..n0+1, c0..c0+3] = X[n0..n0+1, :] @ W_w (+bias on w=0).
// NW weight images staged in LDS; one X-row load feeds 8*NW FMAs per ds_read_b128 pair.
// X row stride KR (pad cols zero); W images consecutive, each CR x CC row-major;
// out stride PC (pad cols get zeros).
template <int KR, int CR, int CC, int PC, int NW, bool BIAS>
__global__ __launch_bounds__(512)
void mmf_kernel(const float* __restrict__ X, const float* __restrict__ W,
                const float* __restrict__ bias,
                float* __restrict__ o0, float* __restrict__ o1,
                float* __restrict__ o2, float* __restrict__ o3, int n) {
    constexpr int CP4 = PC / 4;
    __shared__ __align__(16) float Wl[NW * KR * PC];
    __shared__ __align__(16) float bl[PC];
    for (int i = threadIdx.x; i < NW * KR * PC; i += blockDim.x) {
        int w = i / (KR * PC);
        int r = i - w * KR * PC;
        int k = r / PC, c = r - k * PC;
        Wl[i] = (k < CR && c < CC) ? W[(size_t)w * CR * CC + k * CC + c] : 0.f;
    }
    for (int i = threadIdx.x; i < PC; i += blockDim.x)
        bl[i] = (BIAS && i < CC) ? bias[i] : 0.f;
    __syncthreads();
    int idx = blockIdx.x * blockDim.x + threadIdx.x;
    if (idx >= (n >> 1) * CP4) return;
    int pair = idx / CP4;
    int c0 = (idx - pair * CP4) * 4;
    int n0 = pair * 2;
    const float* xa = X + (size_t)n0 * KR;
    const float* xb = xa + KR;
    float4 acc[2][NW];
    #pragma unroll
    for (int w = 0; w < NW; ++w) {
        acc[0][w] = make_float4(0.f, 0.f, 0.f, 0.f);
        acc[1][w] = acc[0][w];
    }
    if constexpr (BIAS) {
        acc[0][0] = *reinterpret_cast<const float4*>(&bl[c0]);
        acc[1][0] = acc[0][0];
    }
    #pragma unroll 2
    for (int k4 = 0; k4 < KR / 4; ++k4) {
        float4 va = *reinterpret_cast<const float4*>(xa + k4 * 4);
        float4 vb = *reinterpret_cast<const float4*>(xb + k4 * 4);
        #pragma unroll
        for (int j = 0; j < 4; ++j) {
            int k = k4 * 4 + j;
            float sa = (&va.x)[j];
            float sb = (&vb.x)[j];
            #pragma unroll
            for (int w = 0; w < NW; ++w) {
                float4 wv = *reinterpret_cast<const float4*>(&Wl[(w * KR + k) * PC + c0]);
                fma4(acc[0][w], sa, wv);
                fma4(acc[1][w], sb, wv);
            }
        }
    }
    float* outs[4] = {o0, o1, o2, o3};
    #pragma unroll
    for (int w = 0; w < NW; ++w) {
        float* o = outs[w] + (size_t)n0 * PC + c0;
        *reinterpret_cast<float4*>(o) = acc[0][w];
        *reinterpret_cast<float4*>(o + PC) = acc[1][w];
    }
}

// y[n, 0:16] = o2 @ Wmu ; y[n, 16:32] = o2 @ Wls  (bias added in fused final agg)
__global__ void head_mm_kernel(const float* __restrict__ X, const float* __restrict__ Wmu,
                               const float* __restrict__ Wls, float* __restrict__ out, int n) {
    __shared__ __align__(16) float Wl[S2 * 32];
    for (int i = threadIdx.x; i < S2 * 32; i += blockDim.x) {
        int k = i >> 5, c = i & 31;
        Wl[i] = (k < L2C) ? ((c < 16) ? Wmu[k * 16 + c] : Wls[k * 16 + (c - 16)]) : 0.f;
    }
    __syncthreads();
    int idx = blockIdx.x * blockDim.x + threadIdx.x;
    if (idx >= (n >> 1) * 8) return;
    int pair = idx >> 3;
    int c0 = (idx & 7) * 4;
    int n0 = pair * 2;
    const float* x0 = X + (size_t)n0 * S2;
    const float* x1 = x0 + S2;
    float4 z = make_float4(0.f, 0.f, 0.f, 0.f);
    float4 acc0 = z, acc1 = z;
    #pragma unroll 4
    for (int k4 = 0; k4 < S2 / 4; ++k4) {
        float4 xa = *reinterpret_cast<const float4*>(x0 + k4 * 4);
        float4 xb = *reinterpret_cast<const float4*>(x1 + k4 * 4);
        float4 w0 = *reinterpret_cast<const float4*>(&Wl[(k4 * 4 + 0) * 32 + c0]);
        float4 w1 = *reinterpret_cast<const float4*>(&Wl[(k4 * 4 + 1) * 32 + c0]);
        float4 w2 = *reinterpret_cast<const float4*>(&Wl[(k4 * 4 + 2) * 32 + c0]);
        float4 w3 = *reinterpret_cast<const float4*>(&Wl[(k4 * 4 + 3) * 32 + c0]);
        fma4(acc0, xa.x, w0); fma4(acc0, xa.y, w1); fma4(acc0, xa.z, w2); fma4(acc0, xa.w, w3);
        fma4(acc1, xb.x, w0); fma4(acc1, xb.y, w1); fma4(acc1, xb.z, w2); fma4(acc1, xb.w, w3);
    }
    float* o = out + (size_t)n0 * 32 + c0;
    *reinterpret_cast<float4*>(o) = acc0;
    *reinterpret_cast<float4*>(o + 32) = acc1;
}

// ------------------------------------------------------------------ launch

extern "C" void kernel_launch(void* const* d_in, const int* in_sizes, int n_in,
                              void* d_out, int out_size, void* d_ws, size_t ws_size,
                              hipStream_t stream) {
    const float* x   = (const float*)d_in[0];
    const int*   ei  = (const int*)d_in[1];
    const float* W1  = (const float*)d_in[2];
    const float* b1  = (const float*)d_in[3];
    const float* W2  = (const float*)d_in[4];
    const float* b2  = (const float*)d_in[5];
    const float* Wmu = (const float*)d_in[6];
    const float* bmu = (const float*)d_in[7];
    const float* Wls = (const float*)d_in[8];
    const float* bls = (const float*)d_in[9];
    float* out = (float*)d_out;

    const int N = NN, E = EE;
    const int* row = ei;
    const int* col = ei + E;

    // workspace carve-up (256B aligned)
    char* p = (char*)d_ws;
    auto alloc = [&](size_t bytes) -> char* {
        char* r = p;
        p += (bytes + 255) & ~(size_t)255;
        return r;
    };
    int*   deg    = (int*)alloc((size_t)N * 4);
    int*   off    = (int*)alloc((size_t)(N + 1) * 4);
    int*   cursor = (int*)alloc((size_t)N * 4);
    int*   bsum   = (int*)alloc((size_t)256 * 4);
    float* dis    = (float*)alloc((size_t)N * 4);
    float* dis2   = (float*)alloc((size_t)N * 4);
    int2*  eTag   = (int2*)alloc((size_t)E * 8);
    float* y0     = (float*)alloc((size_t)N * S1 * 4);
    float* y1     = (float*)alloc((size_t)N * S1 * 4);
    float* y2     = (float*)alloc((size_t)N * S1 * 4);
    float* y3     = (float*)alloc((size_t)N * S1 * 4);
    // overlay: u0..u3 (N*S2 each) live in y1..y3's space (y1..y3 dead by then)
    float* u0 = y1;
    float* u1 = u0 + (size_t)N * S2;
    float* u2 = u1 + (size_t)N * S2;
    float* u3 = u2 + (size_t)N * S2;
    // overlay: head output lives in u1's space (dead after layer-2 aggs)
    float* yh = u1;

    const int B = 256;
    int gE = (E + B - 1) / B;
    int nb = (N + SB - 1) / SB;  // 196 scan blocks

    // --- graph preprocessing -> CSR by destination
    hipMemsetAsync(deg, 0, (size_t)N * 4, stream);
    hist_kernel<<<gE, B, 0, stream>>>(col, deg, E);
    reduce_kernel<<<nb, SB, 0, stream>>>(deg, bsum, N);
    scan_sums_kernel<<<1, SB, 0, stream>>>(bsum, nb);
    block_scan_kernel<<<nb, SB, 0, stream>>>(deg, bsum, off, cursor, dis, dis2, N);
    fill_kernel<<<gE, B, 0, stream>>>(row, col, dis, cursor, eTag, E);

    // grids
    const int BM = 512;  // fused-mm block size (LDS-limited residency)
    int gmm1 = ((N / 2) * (S1 / 4) + BM - 1) / BM;
    int gmm2 = ((N / 2) * (S2 / 4) + BM - 1) / BM;
    int gmmH = ((N / 2) * 8 + B - 1) / B;
    int ga72 = (N * (S1 / 4) + B - 1) / B;
    int ga44 = (N * (S2 / 4) + B - 1) / B;
    int ga32 = (N * 8 + B - 1) / B;

    // --- TAG layer 1 via Horner: o1 = relu(y0 + A(y1 + A(y2 + A*y3)))
    // Two fused kernels: {W1[0] (+bias), W1[1]} -> y0,y1 ; {W1[2], W1[3]} -> y2,y3
    mmf_kernel<CIN, CIN, L1C, S1, 2, true ><<<gmm1, BM, 0, stream>>>(
        x, W1, b1, y0, y1, nullptr, nullptr, N);
    mmf_kernel<CIN, CIN, L1C, S1, 2, false><<<gmm1, BM, 0, stream>>>(
        x, W1 + 2 * CIN * L1C, nullptr, y2, y3, nullptr, nullptr, N);
    agg_kernel<S1, true, false><<<ga72, B, 0, stream>>>(y3, y2, y2, off, eTag, N);
    agg_kernel<S1, true, false><<<ga72, B, 0, stream>>>(y2, y1, y1, off, eTag, N);
    agg_kernel<S1, true, true ><<<ga72, B, 0, stream>>>(y1, y0, y0, off, eTag, N);
    // o1 = y0 (stride S1, pad cols zero)

    // --- TAG layer 2 via Horner: o2 = relu(u0 + A(u1 + A(u2 + A*u3)))
    // One fused kernel with all four W2 images (reads o1 once).
    mmf_kernel<S1, L1C, L2C, S2, 4, true ><<<gmm2, BM, 0, stream>>>(
        y0, W2, b2, u0, u1, u2, u3, N);
    agg_kernel<S2, true, false><<<ga44, B, 0, stream>>>(u3, u2, u2, off, eTag, N);
    agg_kernel<S2, true, false><<<ga44, B, 0, stream>>>(u2, u1, u1, off, eTag, N);
    agg_kernel<S2, true, true ><<<ga44, B, 0, stream>>>(u1, u0, u0, off, eTag, N);
    // o2 = u0 (stride S2, pad col zero)

    // --- GCN heads: head matmul, then fused agg+self+bias+split-store
    head_mm_kernel<<<gmmH, B, 0, stream>>>(u0, Wmu, Wls, yh, N);
    agg_gcn_final_kernel<<<ga32, B, 0, stream>>>(yh, off, eTag, dis2, bmu, bls, out, N);
}